// Round 12
// baseline (109.291 us; speedup 1.0000x reference)
//
#include <hip/hip_runtime.h>
#include <hip/hip_bf16.h>
#include <stdint.h>

#define M_DIM 2048
#define N_DIM 4096
#define K_DIM 4096

typedef __attribute__((ext_vector_type(8))) __bf16 bf16x8;
typedef __attribute__((ext_vector_type(4))) float f32x4;
typedef __attribute__((ext_vector_type(8))) unsigned short u16x8;

__device__ __constant__ float NF4_TAB[16] = {
    -1.0f, -0.6961928009986877f, -0.5250730514526367f, -0.39491748809814453f,
    -0.28444138169288635f, -0.18477343022823334f, -0.09105003625154495f, 0.0f,
    0.07958029955625534f, 0.16093020141124725f, 0.24611230194568634f,
    0.33791524171829224f, 0.44070982933044434f, 0.5626170039176941f,
    0.7229568362236023f, 1.0f};

// fp32 -> bf16 round-to-nearest-even
__device__ inline unsigned short f2b(float f) {
  union { float f; uint32_t u; } v; v.f = f;
  uint32_t u = v.u;
  return (unsigned short)((u + 0x7fffu + ((u >> 16) & 1u)) >> 16);
}

// ---------------- K1: fused prep -------------------------------------------------
// blocks [0,8192): input cvt; [8192,8448): lora_A cvt; [8448,8704): lora_B cvt;
// [8704,16896): NF4 dequant -> B16 (independent of the cvt segments).
__global__ void __launch_bounds__(256) k_prep(
    const float4* __restrict__ in, ushort4* __restrict__ A16,
    const float4* __restrict__ lA, ushort4* __restrict__ lA16,
    const float4* __restrict__ lB, ushort4* __restrict__ lB16,
    const int* __restrict__ qw, const float* __restrict__ am,
    unsigned short* __restrict__ W) {
  const int b = blockIdx.x;
  const int t = threadIdx.x;
  if (b < 8704) {
    const float4* src;
    ushort4* dst;
    int i;
    if (b < 8192)      { src = in; dst = A16;  i = b * 256 + t; }
    else if (b < 8448) { src = lA; dst = lA16; i = (b - 8192) * 256 + t; }
    else               { src = lB; dst = lB16; i = (b - 8448) * 256 + t; }
    float4 v = src[i];
    ushort4 o;
    o.x = f2b(v.x); o.y = f2b(v.y); o.z = f2b(v.z); o.w = f2b(v.w);
    dst[i] = o;
  } else {
    __shared__ float tab[16];
    if (t < 16) tab[t] = NF4_TAB[t];
    __syncthreads();
    size_t i = (size_t)(b - 8704) * 256 + t;        // group of 8 elems
    int4 q = *(const int4*)(qw + i * 4);
    float amv = am[i >> 3];
    u16x8 o;
    o[0] = f2b(tab[q.x & 15] * amv);  o[1] = f2b(tab[(q.x >> 4) & 15] * amv);
    o[2] = f2b(tab[q.y & 15] * amv);  o[3] = f2b(tab[(q.y >> 4) & 15] * amv);
    o[4] = f2b(tab[q.z & 15] * amv);  o[5] = f2b(tab[(q.z >> 4) & 15] * amv);
    o[6] = f2b(tab[q.w & 15] * amv);  o[7] = f2b(tab[(q.w >> 4) & 15] * amv);
    *(u16x8*)(W + i * 8) = o;
  }
}

// ---------------- K2b: split-K partials of U = A16 @ lora_A16^T ----------------
__global__ void __launch_bounds__(256) k_lora_u(const unsigned short* __restrict__ A16,
                                                const unsigned short* __restrict__ lA16,
                                                float* __restrict__ Up) {
  const int ln = threadIdx.x & 63, w = threadIdx.x >> 6;
  const int lr = ln & 15, lk = ln >> 4;
  const int mslab = blockIdx.x & 15;
  const int kc = blockIdx.x >> 4;          // 16 chunks of 256
  const int m0 = mslab * 128 + w * 32;
  const int k0 = kc * 256;
  f32x4 acc[2][4] = {};
#pragma unroll
  for (int kk = 0; kk < 256; kk += 32) {
    bf16x8 af[2], bv[4];
#pragma unroll
    for (int mi = 0; mi < 2; ++mi)
      af[mi] = *(const bf16x8*)(A16 + (size_t)(m0 + mi * 16 + lr) * K_DIM + k0 + kk + lk * 8);
#pragma unroll
    for (int ni = 0; ni < 4; ++ni)
      bv[ni] = *(const bf16x8*)(lA16 + (size_t)(ni * 16 + lr) * K_DIM + k0 + kk + lk * 8);
#pragma unroll
    for (int mi = 0; mi < 2; ++mi)
#pragma unroll
      for (int ni = 0; ni < 4; ++ni)
        acc[mi][ni] = __builtin_amdgcn_mfma_f32_16x16x32_bf16(af[mi], bv[ni],
                                                              acc[mi][ni], 0, 0, 0);
  }
  float* up = Up + (size_t)kc * (M_DIM * 64);
#pragma unroll
  for (int mi = 0; mi < 2; ++mi)
#pragma unroll
    for (int ni = 0; ni < 4; ++ni)
#pragma unroll
      for (int r = 0; r < 4; ++r)
        up[(size_t)(m0 + mi * 16 + lk * 4 + r) * 64 + ni * 16 + lr] = acc[mi][ni][r];
}

// ---------------- K2c: reduce 16 partials -> bf16 U (deterministic) ------------
__global__ void k_lora_red(const float4* __restrict__ Up, ushort4* __restrict__ U16) {
  int i = blockIdx.x * 256 + threadIdx.x;     // 32768 float4 groups
  float4 s = Up[i];
#pragma unroll
  for (int c = 1; c < 16; ++c) {
    float4 p = Up[(size_t)c * (M_DIM * 64 / 4) + i];
    s.x += p.x; s.y += p.y; s.z += p.z; s.w += p.w;
  }
  ushort4 o; o.x = f2b(s.x); o.y = f2b(s.y); o.z = f2b(s.z); o.w = f2b(s.w);
  U16[i] = o;
}

// ---------------- K3: bf16 GEMM + rank-64 K-extension --------------------------
// BM=128, BN=256, BK=64. 256 threads = 4 waves, 1Mx4N: per-wave output 128x64
// (wave reads full A tile + its own 64 B-rows = 24KB/K-tile; block LDS read
// 96KB vs 128KB for the 8-wave 64x64 decomposition — LDS-BW is the bottleneck).
// 3 rotating LDS buffers; ONE barrier + ONE counted vmcnt(12) per K-tile
// (12 global_load_lds calls per tile at 4 waves). 65 K-tiles (lora tail).
#define LDSBUF 24576  // ushorts per buffer: A 128*64 + B 256*64

#define FENCE() asm volatile("" ::: "memory")
#define BAR() do { FENCE(); __builtin_amdgcn_s_barrier(); FENCE(); } while (0)

__global__ void __launch_bounds__(256, 1) k_gemm(const unsigned short* __restrict__ A,
                                                 const unsigned short* __restrict__ B,
                                                 const unsigned short* __restrict__ U,
                                                 const unsigned short* __restrict__ LB,
                                                 float* __restrict__ C) {
  __shared__ unsigned short lds[3 * LDSBUF];  // 144 KB
  const int tid = threadIdx.x;
  const int ln = tid & 63;
  const int wid = tid >> 6;  // 0..3 = wc (N quadrant); wave spans all 128 M rows
  const int lr = ln & 15;
  const int lk = ln >> 4;

  const int sw = (blockIdx.x & 7) * 32 + (blockIdx.x >> 3);
  const int bm = sw & 15;
  const int bn = sw >> 4;
  const size_t arow0 = (size_t)bm * 128;
  const size_t brow0 = (size_t)bn * 256;

  // staging: one call = 4 waves x 1KB = 32 rows of 128B. A: 4 calls, B: 8 calls.
  const int srow = (wid << 3) + (ln >> 3);   // row within 32-row chunk
  const int gs0 = (ln & 7) ^ (ln >> 3);      // pre-swizzled 16B source slot
  auto stage = [&](const unsigned short* __restrict__ G, size_t stride, size_t grow0,
                   int kt, unsigned short* dst) {
    const char* g = (const char*)(G + (grow0 + srow) * stride) + kt * 128 + gs0 * 16;
    __builtin_amdgcn_global_load_lds(
        (const __attribute__((address_space(1))) uint32_t*)g,
        (__attribute__((address_space(3))) uint32_t*)(dst + (wid << 9)), 16, 0, 0);
  };
  // stage a full K-tile (12 calls): A rows 0..127, B rows 0..255
#define STAGE_TILE(GA, GB, STR, KT, DST)                                         \
  do {                                                                           \
    _Pragma("unroll") for (int c = 0; c < 4; ++c)                                \
      stage(GA, STR, arow0 + c * 32, KT, (DST) + c * 2048);                      \
    _Pragma("unroll") for (int c = 0; c < 8; ++c)                                \
      stage(GB, STR, brow0 + c * 32, KT, (DST) + 8192 + c * 2048);               \
  } while (0)

  f32x4 acc[8][4] = {};

  // prologue: ALL tile-0 loads, then ALL tile-1 loads (vmcnt order matters)
  STAGE_TILE(A, B, (size_t)K_DIM, 0, lds);
  STAGE_TILE(A, B, (size_t)K_DIM, 1, lds + LDSBUF);
  asm volatile("s_waitcnt vmcnt(12)" ::: "memory");  // oldest 12 = tile 0 landed
  BAR();

  int cb = 0, sb = 2;
#pragma unroll 1
  for (int t = 0; t < 65; ++t) {
    const unsigned short* bc = lds + cb * LDSBUF;
    unsigned short* sd = lds + sb * LDSBUF;
    int kt2 = t + 2;
    const bool lora = (kt2 >= 64);
    const unsigned short* GA = lora ? U : A;
    const unsigned short* GB = lora ? LB : B;
    const size_t str = lora ? 64 : (size_t)K_DIM;
    const int ktv = lora ? 0 : kt2;

    // 12 stage issues for K-tile t+2
    STAGE_TILE(GA, GB, str, ktv, sd);

    // 24 ds_read_b128: full A column-slice (8 frags x 2 ks) + own B (4 x 2)
    bf16x8 af[8][2], bv[4][2];
#pragma unroll
    for (int mi = 0; mi < 8; ++mi) {
      int row = mi * 16 + lr;
      int rb = row * 64, x = row & 7;
#pragma unroll
      for (int ks = 0; ks < 2; ++ks) {
        int slot = ((ks << 2) | lk) ^ x;
        af[mi][ks] = *(const bf16x8*)(bc + rb + slot * 8);
      }
    }
#pragma unroll
    for (int ni = 0; ni < 4; ++ni) {
      int row = (wid << 6) + ni * 16 + lr;
      int rb = 8192 + row * 64, x = row & 7;
#pragma unroll
      for (int ks = 0; ks < 2; ++ks) {
        int slot = ((ks << 2) | lk) ^ x;
        bv[ni][ks] = *(const bf16x8*)(bc + rb + slot * 8);
      }
    }

    __builtin_amdgcn_s_setprio(1);
#pragma unroll
    for (int ks = 0; ks < 2; ++ks)
#pragma unroll
      for (int mi = 0; mi < 8; ++mi)
#pragma unroll
        for (int ni = 0; ni < 4; ++ni)
          acc[mi][ni] = __builtin_amdgcn_mfma_f32_16x16x32_bf16(
              af[mi][ks], bv[ni][ks], acc[mi][ni], 0, 0, 0);
    __builtin_amdgcn_s_setprio(0);

    // counted wait: this tile's 12 loads stay in flight; tile t+1's retired.
    // Tail: t=63 issues no stages (outstanding = 12 lora loads from t=62);
    // t=64 needs them -> vmcnt(0) at t=63.
    if (t == 63) {
      asm volatile("s_waitcnt vmcnt(0)" ::: "memory");
    } else {
      asm volatile("s_waitcnt vmcnt(12)" ::: "memory");
    }
    BAR();

    cb = (cb == 2) ? 0 : cb + 1;
    sb = (sb == 2) ? 0 : sb + 1;
    if (t == 62) sb = 3;  // tiles 63,64 issue no stages (sb=3 never used; guard)
    if (t == 63) sb = 3;
  }

  // epilogue: C/D layout col = lane&15, row = (lane>>4)*4 + reg
  float* Cb = C + arow0 * N_DIM + brow0 + (wid << 6);
#pragma unroll
  for (int mi = 0; mi < 8; ++mi)
#pragma unroll
    for (int ni = 0; ni < 4; ++ni)
#pragma unroll
      for (int r = 0; r < 4; ++r)
        Cb[(size_t)(mi * 16 + lk * 4 + r) * N_DIM + ni * 16 + lr] = acc[mi][ni][r];
}

extern "C" void kernel_launch(void* const* d_in, const int* in_sizes, int n_in,
                              void* d_out, int out_size, void* d_ws, size_t ws_size,
                              hipStream_t stream) {
  const float* input  = (const float*)d_in[0];
  const int* qweight  = (const int*)d_in[1];
  const float* absmax = (const float*)d_in[2];
  const float* lora_A = (const float*)d_in[3];
  const float* lora_B = (const float*)d_in[4];
  float* out = (float*)d_out;

  unsigned short* A16  = (unsigned short*)d_ws;                 // 2048*4096 bf16
  unsigned short* B16  = A16 + (size_t)M_DIM * K_DIM;           // 4096*4096 bf16
  unsigned short* lB16 = B16 + (size_t)N_DIM * K_DIM;           // 4096*64
  unsigned short* lA16 = lB16 + (size_t)N_DIM * 64;             // 64*4096
  unsigned short* U16  = lA16 + (size_t)64 * K_DIM;             // 2048*64
  // split-K partials live in d_out (k_gemm overwrites all of d_out afterwards)
  float* Up = out;

  // fused prep: input/lora_A/lora_B cvt + NF4 dequant (all independent)
  k_prep<<<16896, 256, 0, stream>>>((const float4*)input, (ushort4*)A16,
                                    (const float4*)lora_A, (ushort4*)lA16,
                                    (const float4*)lora_B, (ushort4*)lB16,
                                    qweight, absmax, B16);
  // U partials (split-K), then deterministic reduce -> U16
  k_lora_u<<<256, 256, 0, stream>>>(A16, lA16, Up);
  k_lora_red<<<(M_DIM * 64 / 4) / 256, 256, 0, stream>>>((const float4*)Up,
                                                         (ushort4*)U16);
  // C = [A16 | U] @ [B16 | lB16]^T
  k_gemm<<<256, 256, 0, stream>>>(A16, B16, U16, lB16, out);
}

// Round 13
// 101.806 us; speedup vs baseline: 1.0735x; 1.0735x over previous
//
#include <hip/hip_runtime.h>
#include <hip/hip_bf16.h>
#include <stdint.h>

#define M_DIM 2048
#define N_DIM 4096
#define K_DIM 4096

typedef __attribute__((ext_vector_type(8))) __bf16 bf16x8;
typedef __attribute__((ext_vector_type(4))) float f32x4;
typedef __attribute__((ext_vector_type(8))) unsigned short u16x8;

__device__ __constant__ float NF4_TAB[16] = {
    -1.0f, -0.6961928009986877f, -0.5250730514526367f, -0.39491748809814453f,
    -0.28444138169288635f, -0.18477343022823334f, -0.09105003625154495f, 0.0f,
    0.07958029955625534f, 0.16093020141124725f, 0.24611230194568634f,
    0.33791524171829224f, 0.44070982933044434f, 0.5626170039176941f,
    0.7229568362236023f, 1.0f};

// fp32 -> bf16 round-to-nearest-even
__device__ inline unsigned short f2b(float f) {
  union { float f; uint32_t u; } v; v.f = f;
  uint32_t u = v.u;
  return (unsigned short)((u + 0x7fffu + ((u >> 16) & 1u)) >> 16);
}

// ---------------- K1: fused prep -------------------------------------------------
// blocks [0,8192): input cvt; [8192,8448): lora_A cvt; [8448,8704): lora_B cvt;
// [8704,16896): NF4 dequant -> B16 (independent of the cvt segments).
__global__ void __launch_bounds__(256) k_prep(
    const float4* __restrict__ in, ushort4* __restrict__ A16,
    const float4* __restrict__ lA, ushort4* __restrict__ lA16,
    const float4* __restrict__ lB, ushort4* __restrict__ lB16,
    const int* __restrict__ qw, const float* __restrict__ am,
    unsigned short* __restrict__ W) {
  const int b = blockIdx.x;
  const int t = threadIdx.x;
  if (b < 8704) {
    const float4* src;
    ushort4* dst;
    int i;
    if (b < 8192)      { src = in; dst = A16;  i = b * 256 + t; }
    else if (b < 8448) { src = lA; dst = lA16; i = (b - 8192) * 256 + t; }
    else               { src = lB; dst = lB16; i = (b - 8448) * 256 + t; }
    float4 v = src[i];
    ushort4 o;
    o.x = f2b(v.x); o.y = f2b(v.y); o.z = f2b(v.z); o.w = f2b(v.w);
    dst[i] = o;
  } else {
    __shared__ float tab[16];
    if (t < 16) tab[t] = NF4_TAB[t];
    __syncthreads();
    size_t i = (size_t)(b - 8704) * 256 + t;        // group of 8 elems
    int4 q = *(const int4*)(qw + i * 4);
    float amv = am[i >> 3];
    u16x8 o;
    o[0] = f2b(tab[q.x & 15] * amv);  o[1] = f2b(tab[(q.x >> 4) & 15] * amv);
    o[2] = f2b(tab[q.y & 15] * amv);  o[3] = f2b(tab[(q.y >> 4) & 15] * amv);
    o[4] = f2b(tab[q.z & 15] * amv);  o[5] = f2b(tab[(q.z >> 4) & 15] * amv);
    o[6] = f2b(tab[q.w & 15] * amv);  o[7] = f2b(tab[(q.w >> 4) & 15] * amv);
    *(u16x8*)(W + i * 8) = o;
  }
}

// ---------------- K2b: split-K partials of U = A16 @ lora_A16^T ----------------
__global__ void __launch_bounds__(256) k_lora_u(const unsigned short* __restrict__ A16,
                                                const unsigned short* __restrict__ lA16,
                                                float* __restrict__ Up) {
  const int ln = threadIdx.x & 63, w = threadIdx.x >> 6;
  const int lr = ln & 15, lk = ln >> 4;
  const int mslab = blockIdx.x & 15;
  const int kc = blockIdx.x >> 4;          // 16 chunks of 256
  const int m0 = mslab * 128 + w * 32;
  const int k0 = kc * 256;
  f32x4 acc[2][4] = {};
#pragma unroll
  for (int kk = 0; kk < 256; kk += 32) {
    bf16x8 af[2], bv[4];
#pragma unroll
    for (int mi = 0; mi < 2; ++mi)
      af[mi] = *(const bf16x8*)(A16 + (size_t)(m0 + mi * 16 + lr) * K_DIM + k0 + kk + lk * 8);
#pragma unroll
    for (int ni = 0; ni < 4; ++ni)
      bv[ni] = *(const bf16x8*)(lA16 + (size_t)(ni * 16 + lr) * K_DIM + k0 + kk + lk * 8);
#pragma unroll
    for (int mi = 0; mi < 2; ++mi)
#pragma unroll
      for (int ni = 0; ni < 4; ++ni)
        acc[mi][ni] = __builtin_amdgcn_mfma_f32_16x16x32_bf16(af[mi], bv[ni],
                                                              acc[mi][ni], 0, 0, 0);
  }
  float* up = Up + (size_t)kc * (M_DIM * 64);
#pragma unroll
  for (int mi = 0; mi < 2; ++mi)
#pragma unroll
    for (int ni = 0; ni < 4; ++ni)
#pragma unroll
      for (int r = 0; r < 4; ++r)
        up[(size_t)(m0 + mi * 16 + lk * 4 + r) * 64 + ni * 16 + lr] = acc[mi][ni][r];
}

// ---------------- K2c: reduce 16 partials -> bf16 U (deterministic) ------------
__global__ void k_lora_red(const float4* __restrict__ Up, ushort4* __restrict__ U16) {
  int i = blockIdx.x * 256 + threadIdx.x;     // 32768 float4 groups
  float4 s = Up[i];
#pragma unroll
  for (int c = 1; c < 16; ++c) {
    float4 p = Up[(size_t)c * (M_DIM * 64 / 4) + i];
    s.x += p.x; s.y += p.y; s.z += p.z; s.w += p.w;
  }
  ushort4 o; o.x = f2b(s.x); o.y = f2b(s.y); o.z = f2b(s.z); o.w = f2b(s.w);
  U16[i] = o;
}

// ---------------- K3: bf16 GEMM + rank-64 K-extension (R11 config, best) -------
// BM=128, BN=256, BK=64. 8 waves 2Mx4N, wave tile 64x64 (LDS-traffic-optimal at
// 2 waves/SIMD: 176KB/K-tile @ ~210B/cyc == MFMA 310cyc/0.37 — measured on the
// LDS-BW roofline; 1 wave/SIMD (R12) and 4 waves/SIMD (computed) are both worse).
// 3 rotating LDS buffers; ONE barrier + ONE counted vmcnt(6) per K-tile.
#define LDSBUF 24576  // ushorts per buffer: A 128*64 + B 256*64

#define FENCE() asm volatile("" ::: "memory")
#define BAR() do { FENCE(); __builtin_amdgcn_s_barrier(); FENCE(); } while (0)

__global__ void __launch_bounds__(512, 2) k_gemm(const unsigned short* __restrict__ A,
                                                 const unsigned short* __restrict__ B,
                                                 const unsigned short* __restrict__ U,
                                                 const unsigned short* __restrict__ LB,
                                                 float* __restrict__ C) {
  __shared__ unsigned short lds[3 * LDSBUF];  // 144 KB
  const int tid = threadIdx.x;
  const int ln = tid & 63;
  const int wid = tid >> 6;  // 0..7
  const int wr = wid >> 2;   // 0..1  (M)
  const int wc = wid & 3;    // 0..3  (N)
  const int lr = ln & 15;
  const int lk = ln >> 4;

  const int sw = (blockIdx.x & 7) * 32 + (blockIdx.x >> 3);
  const int bm = sw & 15;
  const int bn = sw >> 4;
  const size_t arow0 = (size_t)bm * 128;
  const size_t brow0 = (size_t)bn * 256;

  const int srow = (wid << 3) + (ln >> 3);
  const int gs0 = (ln & 7) ^ (srow & 7);
  auto stage = [&](const unsigned short* __restrict__ G, size_t stride, size_t grow0,
                   int kt, unsigned short* dst) {
    const char* g = (const char*)(G + (grow0 + srow) * stride) + kt * 128 + gs0 * 16;
    __builtin_amdgcn_global_load_lds(
        (const __attribute__((address_space(1))) uint32_t*)g,
        (__attribute__((address_space(3))) uint32_t*)(dst + (size_t)(wid << 3) * 64),
        16, 0, 0);
  };

  f32x4 acc[4][4] = {};

  // prologue: K-tiles 0,1 (both regular)
  stage(A, K_DIM, arow0, 0, lds);
  stage(A, K_DIM, arow0 + 64, 0, lds + 4096);
  stage(B, K_DIM, brow0, 0, lds + 8192);
  stage(B, K_DIM, brow0 + 64, 0, lds + 12288);
  stage(B, K_DIM, brow0 + 128, 0, lds + 16384);
  stage(B, K_DIM, brow0 + 192, 0, lds + 20480);
  {
    unsigned short* b1 = lds + LDSBUF;
    stage(A, K_DIM, arow0, 1, b1);
    stage(A, K_DIM, arow0 + 64, 1, b1 + 4096);
    stage(B, K_DIM, brow0, 1, b1 + 8192);
    stage(B, K_DIM, brow0 + 64, 1, b1 + 12288);
    stage(B, K_DIM, brow0 + 128, 1, b1 + 16384);
    stage(B, K_DIM, brow0 + 192, 1, b1 + 20480);
  }
  asm volatile("s_waitcnt vmcnt(6)" ::: "memory");  // K-tile 0 landed; K1 in flight
  BAR();

  int cb = 0, sb = 2;
#pragma unroll 1
  for (int t = 0; t < 65; ++t) {
    const unsigned short* bc = lds + cb * LDSBUF;
    unsigned short* sd = lds + sb * LDSBUF;
    int kt2 = t + 2;
    const bool lora = (kt2 >= 64);
    const unsigned short* GA = lora ? U : A;
    const unsigned short* GB = lora ? LB : B;
    const size_t str = lora ? 64 : (size_t)K_DIM;
    const int ktv = lora ? 0 : kt2;

    // 6 stage issues for K-tile t+2 (HBM latency hides under this whole tile)
    stage(GA, str, arow0, ktv, sd);
    stage(GA, str, arow0 + 64, ktv, sd + 4096);
    stage(GB, str, brow0, ktv, sd + 8192);
    stage(GB, str, brow0 + 64, ktv, sd + 12288);
    stage(GB, str, brow0 + 128, ktv, sd + 16384);
    stage(GB, str, brow0 + 192, ktv, sd + 20480);

    // 16 ds_read_b128 (both K-halves), compiler interleaves lgkmcnt with MFMA
    bf16x8 af[4][2], bv[4][2];
#pragma unroll
    for (int mi = 0; mi < 4; ++mi) {
      int row = wr * 64 + mi * 16 + lr;
      int rb = row * 64, x = row & 7;
#pragma unroll
      for (int ks = 0; ks < 2; ++ks) {
        int slot = ((ks << 2) | lk) ^ x;
        af[mi][ks] = *(const bf16x8*)(bc + rb + slot * 8);
      }
    }
#pragma unroll
    for (int ni = 0; ni < 4; ++ni) {
      int row = wc * 64 + ni * 16 + lr;
      int rb = 8192 + row * 64, x = row & 7;
#pragma unroll
      for (int ks = 0; ks < 2; ++ks) {
        int slot = ((ks << 2) | lk) ^ x;
        bv[ni][ks] = *(const bf16x8*)(bc + rb + slot * 8);
      }
    }

    __builtin_amdgcn_s_setprio(1);
#pragma unroll
    for (int ks = 0; ks < 2; ++ks)
#pragma unroll
      for (int mi = 0; mi < 4; ++mi)
#pragma unroll
        for (int ni = 0; ni < 4; ++ni)
          acc[mi][ni] = __builtin_amdgcn_mfma_f32_16x16x32_bf16(
              af[mi][ks], bv[ni][ks], acc[mi][ni], 0, 0, 0);
    __builtin_amdgcn_s_setprio(0);

    // counted wait: this tile's 6 loads stay in flight; tile t+1's are complete
    asm volatile("s_waitcnt vmcnt(6)" ::: "memory");
    BAR();

    cb = (cb == 2) ? 0 : cb + 1;
    sb = (sb == 2) ? 0 : sb + 1;
  }

  // epilogue: C/D layout col = lane&15, row = (lane>>4)*4 + reg
  float* Cb = C + (arow0 + (size_t)wr * 64) * N_DIM + brow0 + wc * 64;
#pragma unroll
  for (int mi = 0; mi < 4; ++mi)
#pragma unroll
    for (int ni = 0; ni < 4; ++ni)
#pragma unroll
      for (int r = 0; r < 4; ++r)
        Cb[(size_t)(mi * 16 + lk * 4 + r) * N_DIM + ni * 16 + lr] = acc[mi][ni][r];
}

extern "C" void kernel_launch(void* const* d_in, const int* in_sizes, int n_in,
                              void* d_out, int out_size, void* d_ws, size_t ws_size,
                              hipStream_t stream) {
  const float* input  = (const float*)d_in[0];
  const int* qweight  = (const int*)d_in[1];
  const float* absmax = (const float*)d_in[2];
  const float* lora_A = (const float*)d_in[3];
  const float* lora_B = (const float*)d_in[4];
  float* out = (float*)d_out;

  unsigned short* A16  = (unsigned short*)d_ws;                 // 2048*4096 bf16
  unsigned short* B16  = A16 + (size_t)M_DIM * K_DIM;           // 4096*4096 bf16
  unsigned short* lB16 = B16 + (size_t)N_DIM * K_DIM;           // 4096*64
  unsigned short* lA16 = lB16 + (size_t)N_DIM * 64;             // 64*4096
  unsigned short* U16  = lA16 + (size_t)64 * K_DIM;             // 2048*64
  // split-K partials live in d_out (k_gemm overwrites all of d_out afterwards)
  float* Up = out;

  // fused prep: input/lora_A/lora_B cvt + NF4 dequant (all independent)
  k_prep<<<16896, 256, 0, stream>>>((const float4*)input, (ushort4*)A16,
                                    (const float4*)lora_A, (ushort4*)lA16,
                                    (const float4*)lora_B, (ushort4*)lB16,
                                    qweight, absmax, B16);
  // U partials (split-K), then deterministic reduce -> U16
  k_lora_u<<<256, 256, 0, stream>>>(A16, lA16, Up);
  k_lora_red<<<(M_DIM * 64 / 4) / 256, 256, 0, stream>>>((const float4*)Up,
                                                         (ushort4*)U16);
  // C = [A16 | U] @ [B16 | lB16]^T
  k_gemm<<<256, 512, 0, stream>>>(A16, B16, U16, lB16, out);
}